// Round 2
// baseline (3110.625 us; speedup 1.0000x reference)
//
#include <hip/hip_runtime.h>
#include <math.h>

#define F 128
#define NPB 16  // nodes per block in fused layer kernel

__global__ __launch_bounds__(256) void k_deg(const int* __restrict__ src,
                                             int* __restrict__ deg, int E) {
  for (int i = blockIdx.x * 256 + threadIdx.x; i < E; i += gridDim.x * 256)
    atomicAdd(&deg[src[i]], 1);
}

__global__ __launch_bounds__(256) void k_dinv(const int* __restrict__ deg,
                                              float* __restrict__ dinv, int N) {
  int i = blockIdx.x * 256 + threadIdx.x;
  if (i < N) {
    int d = deg[i];
    dinv[i] = d > 0 ? rsqrtf((float)d) : 0.0f;
  }
}

// acc[dst] += dinv[src] * x[src]  (row of 128 floats; 32 lanes/edge, float4 each)
__global__ __launch_bounds__(256) void k_scatter1(const int* __restrict__ src,
                                                  const int* __restrict__ dst,
                                                  const float* __restrict__ x,
                                                  const float* __restrict__ dinv,
                                                  float* __restrict__ acc, int E) {
  int t = blockIdx.x * 256 + threadIdx.x;
  int e = t >> 5;
  if (e >= E) return;
  int lane = t & 31;
  int s = src[e];
  int d = dst[e];
  float us = dinv[s];  // s appears as a src => deg[s] >= 1 => us > 0
  float4 v = ((const float4*)(x + (size_t)s * F))[lane];
  float* a = acc + (size_t)d * F + lane * 4;
  atomicAdd(a + 0, us * v.x);
  atomicAdd(a + 1, us * v.y);
  atomicAdd(a + 2, us * v.z);
  atomicAdd(a + 3, us * v.w);
}

// Fused: h = relu(x@w10 + t@w11 + b1) with t = -dinv[i]*acc[i]; then
// p[i] = h . w20 ; q[i] = dinv[i] * (h . w21). h never hits global memory.
// Block: 64 threads (1 wave), thread t owns features {t, t+64}, 16 nodes/block.
__global__ __launch_bounds__(64) void k_layer(
    const float* __restrict__ x, const float* __restrict__ acc,
    const float* __restrict__ dinv, const float* __restrict__ w10,
    const float* __restrict__ w11, const float* __restrict__ b1,
    const float* __restrict__ w20, const float* __restrict__ w21,
    float* __restrict__ p, float* __restrict__ q, int N) {
  __shared__ float xs[NPB][F];
  __shared__ float ts[NPB][F];
  __shared__ float us[NPB];
  int node0 = blockIdx.x * NPB;
  int tid = threadIdx.x;
  if (tid < NPB) {
    int gn = node0 + tid;
    us[tid] = (gn < N) ? dinv[gn] : 0.0f;
  }
  __syncthreads();
  for (int idx = tid; idx < NPB * F; idx += 64) {
    int n = idx >> 7, k = idx & 127;
    int gn = node0 + n;
    float xv = 0.f, av = 0.f;
    if (gn < N) {
      xv = x[(size_t)gn * F + k];
      av = acc[(size_t)gn * F + k];
    }
    xs[n][k] = xv;
    ts[n][k] = -us[n] * av;
  }
  __syncthreads();
  const int f0 = tid, f1 = tid + 64;
  float h0[NPB], h1[NPB];
#pragma unroll
  for (int n = 0; n < NPB; ++n) {
    h0[n] = 0.f;
    h1[n] = 0.f;
  }
  for (int k4 = 0; k4 < F / 4; ++k4) {
    int k = k4 * 4;
    float a00 = w10[(k + 0) * F + f0], a01 = w10[(k + 1) * F + f0];
    float a02 = w10[(k + 2) * F + f0], a03 = w10[(k + 3) * F + f0];
    float a10 = w10[(k + 0) * F + f1], a11 = w10[(k + 1) * F + f1];
    float a12 = w10[(k + 2) * F + f1], a13 = w10[(k + 3) * F + f1];
    float c00 = w11[(k + 0) * F + f0], c01 = w11[(k + 1) * F + f0];
    float c02 = w11[(k + 2) * F + f0], c03 = w11[(k + 3) * F + f0];
    float c10 = w11[(k + 0) * F + f1], c11 = w11[(k + 1) * F + f1];
    float c12 = w11[(k + 2) * F + f1], c13 = w11[(k + 3) * F + f1];
#pragma unroll
    for (int n = 0; n < NPB; ++n) {
      float4 xv = *(const float4*)&xs[n][k];
      float4 tv = *(const float4*)&ts[n][k];
      h0[n] += xv.x * a00 + xv.y * a01 + xv.z * a02 + xv.w * a03 +
               tv.x * c00 + tv.y * c01 + tv.z * c02 + tv.w * c03;
      h1[n] += xv.x * a10 + xv.y * a11 + xv.z * a12 + xv.w * a13 +
               tv.x * c10 + tv.y * c11 + tv.z * c12 + tv.w * c13;
    }
  }
  float bf0 = b1[f0], bf1 = b1[f1];
  float w20f0 = w20[f0], w20f1 = w20[f1];
  float w21f0 = w21[f0], w21f1 = w21[f1];
#pragma unroll
  for (int n = 0; n < NPB; ++n) {
    float hh0 = fmaxf(h0[n] + bf0, 0.f);
    float hh1 = fmaxf(h1[n] + bf1, 0.f);
    float pp = hh0 * w20f0 + hh1 * w20f1;
    float qq = hh0 * w21f0 + hh1 * w21f1;
#pragma unroll
    for (int off = 32; off > 0; off >>= 1) {
      pp += __shfl_down(pp, off);
      qq += __shfl_down(qq, off);
    }
    if (tid == 0) {
      int gn = node0 + n;
      if (gn < N) {
        p[gn] = pp;
        q[gn] = us[n] * qq;
      }
    }
  }
}

__global__ __launch_bounds__(256) void k_scatter2(const int* __restrict__ src,
                                                  const int* __restrict__ dst,
                                                  const float* __restrict__ q,
                                                  float* __restrict__ acc2, int E) {
  for (int e = blockIdx.x * 256 + threadIdx.x; e < E; e += gridDim.x * 256)
    atomicAdd(&acc2[dst[e]], q[src[e]]);
}

__global__ __launch_bounds__(256) void k_final(const float* __restrict__ p,
                                               const float* __restrict__ acc2,
                                               const float* __restrict__ dinv,
                                               const float* __restrict__ b2,
                                               float* __restrict__ out, int N) {
  int i = blockIdx.x * 256 + threadIdx.x;
  if (i < N) {
    float z = p[i] - dinv[i] * acc2[i] + b2[0];
    out[i] = 1.0f / (1.0f + expf(-z));
  }
}

extern "C" void kernel_launch(void* const* d_in, const int* in_sizes, int n_in,
                              void* d_out, int out_size, void* d_ws, size_t ws_size,
                              hipStream_t stream) {
  const float* x = (const float*)d_in[0];
  const int* ei = (const int*)d_in[1];
  const float* w10 = (const float*)d_in[2];
  const float* w11 = (const float*)d_in[3];
  const float* b1 = (const float*)d_in[4];
  const float* w20 = (const float*)d_in[5];
  const float* w21 = (const float*)d_in[6];
  const float* b2 = (const float*)d_in[7];
  float* out = (float*)d_out;
  int N = in_sizes[0] / F;
  int E = in_sizes[1] / 2;
  const int* src = ei;
  const int* dst = ei + E;

  // workspace layout: acc N*F | dinv N | p N | q N | acc2 N | deg N
  size_t need = ((size_t)N * F + 5 * (size_t)N) * sizeof(float);
  if (ws_size < need) return;  // clean fail instead of OOB container kill

  float* acc = (float*)d_ws;            // N*F
  float* dinv = acc + (size_t)N * F;    // N
  float* p = dinv + N;                  // N
  float* q = p + N;                     // N
  float* acc2 = q + N;                  // N
  int* deg = (int*)(acc2 + N);          // N

  hipMemsetAsync(acc, 0, (size_t)N * F * sizeof(float), stream);
  hipMemsetAsync(acc2, 0, (size_t)N * sizeof(float), stream);
  hipMemsetAsync(deg, 0, (size_t)N * sizeof(int), stream);

  k_deg<<<4096, 256, 0, stream>>>(src, deg, E);
  k_dinv<<<(N + 255) / 256, 256, 0, stream>>>(deg, dinv, N);
  k_scatter1<<<(int)(((size_t)E * 32 + 255) / 256), 256, 0, stream>>>(src, dst, x,
                                                                      dinv, acc, E);
  k_layer<<<(N + NPB - 1) / NPB, 64, 0, stream>>>(x, acc, dinv, w10, w11, b1, w20,
                                                  w21, p, q, N);
  k_scatter2<<<4096, 256, 0, stream>>>(src, dst, q, acc2, E);
  k_final<<<(N + 255) / 256, 256, 0, stream>>>(p, acc2, dinv, b2, out, N);
}

// Round 4
// 660.657 us; speedup vs baseline: 4.7084x; 4.7084x over previous
//
#include <hip/hip_runtime.h>
#include <math.h>

#define F 128
#define NPB 16         // nodes per block in fused layer kernel
#define SCAN_CHUNK 1024

// ---------- degree count (both endpoints) ----------
__global__ __launch_bounds__(256) void k_deg2(const int* __restrict__ src,
                                              const int* __restrict__ dst,
                                              int* __restrict__ degA,
                                              int* __restrict__ degB, int E) {
  for (int i = blockIdx.x * 256 + threadIdx.x; i < E; i += gridDim.x * 256) {
    atomicAdd(&degA[src[i]], 1);
    atomicAdd(&degB[dst[i]], 1);
  }
}

__global__ __launch_bounds__(256) void k_dinv(const int* __restrict__ deg,
                                              float* __restrict__ dinv, int N) {
  int i = blockIdx.x * 256 + threadIdx.x;
  if (i < N) {
    int d = deg[i];
    dinv[i] = d > 0 ? rsqrtf((float)d) : 0.0f;
  }
}

// ---------- CSR build: 3-phase exclusive scan of in-degrees ----------
__global__ __launch_bounds__(256) void k_scanA(const int* __restrict__ deg,
                                               int* __restrict__ rp,
                                               int* __restrict__ bsum, int N) {
  __shared__ int sh[256];
  int tid = threadIdx.x;
  int base = blockIdx.x * SCAN_CHUNK + tid * 4;
  int v0 = 0, v1 = 0, v2 = 0, v3 = 0;
  if (base + 0 < N) v0 = deg[base + 0];
  if (base + 1 < N) v1 = deg[base + 1];
  if (base + 2 < N) v2 = deg[base + 2];
  if (base + 3 < N) v3 = deg[base + 3];
  int ts = v0 + v1 + v2 + v3;
  int val = ts;
  sh[tid] = val;
  __syncthreads();
  for (int off = 1; off < 256; off <<= 1) {
    int other = (tid >= off) ? sh[tid - off] : 0;
    __syncthreads();
    val += other;
    sh[tid] = val;
    __syncthreads();
  }
  int excl = val - ts;
  if (base + 0 < N) rp[base + 0] = excl;
  if (base + 1 < N) rp[base + 1] = excl + v0;
  if (base + 2 < N) rp[base + 2] = excl + v0 + v1;
  if (base + 3 < N) rp[base + 3] = excl + v0 + v1 + v2;
  if (tid == 255) bsum[blockIdx.x] = val;
}

__global__ __launch_bounds__(256) void k_scanB(int* __restrict__ bsum, int nb) {
  __shared__ int sh[256];
  int tid = threadIdx.x;
  int ts = (tid < nb) ? bsum[tid] : 0;
  int val = ts;
  sh[tid] = val;
  __syncthreads();
  for (int off = 1; off < 256; off <<= 1) {
    int other = (tid >= off) ? sh[tid - off] : 0;
    __syncthreads();
    val += other;
    sh[tid] = val;
    __syncthreads();
  }
  if (tid < nb) bsum[tid] = val - ts;  // exclusive
}

__global__ __launch_bounds__(256) void k_scanC(int* __restrict__ rp,
                                               const int* __restrict__ bsum,
                                               int* __restrict__ pos, int N, int E) {
  int i = blockIdx.x * 256 + threadIdx.x;
  if (i < N) {
    int v = rp[i] + bsum[i >> 10];
    rp[i] = v;
    pos[i] = v;
  }
  if (i == 0) rp[N] = E;
}

__global__ __launch_bounds__(256) void k_fill(const int* __restrict__ src,
                                              const int* __restrict__ dst,
                                              const float* __restrict__ dinv,
                                              int* __restrict__ pos,
                                              int2* __restrict__ pairs, int E) {
  for (int e = blockIdx.x * 256 + threadIdx.x; e < E; e += gridDim.x * 256) {
    int s = src[e];
    int d = dst[e];
    int idx = atomicAdd(&pos[d], 1);
    pairs[idx] = make_int2(s, __float_as_int(dinv[s]));
  }
}

// ---------- path A: aggregation by gather, one wave per node ----------
// acc[i] = -dinv[i] * sum_{e: dst=i} dinv[src] * x[src]   (row of 128 floats)
__global__ __launch_bounds__(256) void k_gather1(const int2* __restrict__ pairs,
                                                 const int* __restrict__ rp,
                                                 const float* __restrict__ x,
                                                 const float* __restrict__ dinv,
                                                 float* __restrict__ acc, int N) {
  int wave = (blockIdx.x * 256 + threadIdx.x) >> 6;
  int lane = threadIdx.x & 63;
  if (wave >= N) return;
  int beg = rp[wave], end = rp[wave + 1];
  const float2* x2 = (const float2*)x;
  float ax = 0.f, ay = 0.f;
  int j = beg;
  for (; j + 1 < end; j += 2) {
    int2 p0 = pairs[j];
    int2 p1 = pairs[j + 1];
    float w0 = __int_as_float(p0.y);
    float w1 = __int_as_float(p1.y);
    float2 v0 = x2[(size_t)p0.x * 64 + lane];
    float2 v1 = x2[(size_t)p1.x * 64 + lane];
    ax += w0 * v0.x + w1 * v1.x;
    ay += w0 * v0.y + w1 * v1.y;
  }
  if (j < end) {
    int2 p0 = pairs[j];
    float w0 = __int_as_float(p0.y);
    float2 v0 = x2[(size_t)p0.x * 64 + lane];
    ax += w0 * v0.x;
    ay += w0 * v0.y;
  }
  float di = dinv[wave];
  ((float2*)acc)[(size_t)wave * 64 + lane] = make_float2(-di * ax, -di * ay);
}

// ---------- fused layer GEMM: h = relu(x@w10 + ts@w11 + b1); p = h.w20; r = h.w21
// 64 threads (1 wave), thread owns features {tid, tid+64}, NPB nodes per block.
__global__ __launch_bounds__(64) void k_layer(
    const float* __restrict__ x, const float* __restrict__ tsrc,
    const float* __restrict__ w10, const float* __restrict__ w11,
    const float* __restrict__ b1, const float* __restrict__ w20,
    const float* __restrict__ w21, float* __restrict__ p, float* __restrict__ r,
    int N) {
  __shared__ float xs[NPB][F];
  __shared__ float ts[NPB][F];
  int node0 = blockIdx.x * NPB;
  int tid = threadIdx.x;
  for (int idx = tid; idx < NPB * F; idx += 64) {
    int n = idx >> 7, k = idx & 127;
    int gn = node0 + n;
    float xv = 0.f, av = 0.f;
    if (gn < N) {
      xv = x[(size_t)gn * F + k];
      av = tsrc[(size_t)gn * F + k];
    }
    xs[n][k] = xv;
    ts[n][k] = av;
  }
  __syncthreads();
  const int f0 = tid, f1 = tid + 64;
  float h0[NPB], h1[NPB];
#pragma unroll
  for (int n = 0; n < NPB; ++n) { h0[n] = 0.f; h1[n] = 0.f; }
  for (int k4 = 0; k4 < F / 4; ++k4) {
    int k = k4 * 4;
    float a00 = w10[(k + 0) * F + f0], a01 = w10[(k + 1) * F + f0];
    float a02 = w10[(k + 2) * F + f0], a03 = w10[(k + 3) * F + f0];
    float a10 = w10[(k + 0) * F + f1], a11 = w10[(k + 1) * F + f1];
    float a12 = w10[(k + 2) * F + f1], a13 = w10[(k + 3) * F + f1];
    float c00 = w11[(k + 0) * F + f0], c01 = w11[(k + 1) * F + f0];
    float c02 = w11[(k + 2) * F + f0], c03 = w11[(k + 3) * F + f0];
    float c10 = w11[(k + 0) * F + f1], c11 = w11[(k + 1) * F + f1];
    float c12 = w11[(k + 2) * F + f1], c13 = w11[(k + 3) * F + f1];
#pragma unroll
    for (int n = 0; n < NPB; ++n) {
      float4 xv = *(const float4*)&xs[n][k];
      float4 tv = *(const float4*)&ts[n][k];
      h0[n] += xv.x * a00 + xv.y * a01 + xv.z * a02 + xv.w * a03 +
               tv.x * c00 + tv.y * c01 + tv.z * c02 + tv.w * c03;
      h1[n] += xv.x * a10 + xv.y * a11 + xv.z * a12 + xv.w * a13 +
               tv.x * c10 + tv.y * c11 + tv.z * c12 + tv.w * c13;
    }
  }
  float bf0 = b1[f0], bf1 = b1[f1];
  float w20f0 = w20[f0], w20f1 = w20[f1];
  float w21f0 = w21[f0], w21f1 = w21[f1];
#pragma unroll
  for (int n = 0; n < NPB; ++n) {
    float hh0 = fmaxf(h0[n] + bf0, 0.f);
    float hh1 = fmaxf(h1[n] + bf1, 0.f);
    float pp = hh0 * w20f0 + hh1 * w20f1;
    float qq = hh0 * w21f0 + hh1 * w21f1;
#pragma unroll
    for (int off = 32; off > 0; off >>= 1) {
      pp += __shfl_down(pp, off);
      qq += __shfl_down(qq, off);
    }
    if (tid == 0) {
      int gn = node0 + n;
      if (gn < N) { p[gn] = pp; r[gn] = qq; }
    }
  }
}

// ---------- path B: layer with neighborhood gather fused (no acc buffer) ----------
__global__ __launch_bounds__(64) void k_layer_fused(
    const int2* __restrict__ pairs, const int* __restrict__ rp,
    const float* __restrict__ x, const float* __restrict__ dinv,
    const float* __restrict__ w10, const float* __restrict__ w11,
    const float* __restrict__ b1, const float* __restrict__ w20,
    const float* __restrict__ w21, float* __restrict__ p, float* __restrict__ r,
    int N) {
  __shared__ float xs[NPB][F];
  __shared__ float ts[NPB][F];
  int node0 = blockIdx.x * NPB;
  int tid = threadIdx.x;  // 0..63
  for (int idx = tid; idx < NPB * F; idx += 64) {
    int n = idx >> 7, k = idx & 127;
    int gn = node0 + n;
    xs[n][k] = (gn < N) ? x[(size_t)gn * F + k] : 0.f;
  }
  const float2* x2 = (const float2*)x;
#pragma unroll 1
  for (int n = 0; n < NPB; ++n) {
    int gn = node0 + n;
    float ax = 0.f, ay = 0.f;
    if (gn < N) {
      int beg = rp[gn], end = rp[gn + 1];
      int j = beg;
      for (; j + 1 < end; j += 2) {
        int2 p0 = pairs[j];
        int2 p1 = pairs[j + 1];
        float w0 = __int_as_float(p0.y);
        float w1 = __int_as_float(p1.y);
        float2 v0 = x2[(size_t)p0.x * 64 + tid];
        float2 v1 = x2[(size_t)p1.x * 64 + tid];
        ax += w0 * v0.x + w1 * v1.x;
        ay += w0 * v0.y + w1 * v1.y;
      }
      if (j < end) {
        int2 p0 = pairs[j];
        float w0 = __int_as_float(p0.y);
        float2 v0 = x2[(size_t)p0.x * 64 + tid];
        ax += w0 * v0.x;
        ay += w0 * v0.y;
      }
      float di = dinv[gn];
      ax *= -di;
      ay *= -di;
    }
    ((float2*)&ts[n][0])[tid] = make_float2(ax, ay);
  }
  __syncthreads();
  const int f0 = tid, f1 = tid + 64;
  float h0[NPB], h1[NPB];
#pragma unroll
  for (int n = 0; n < NPB; ++n) { h0[n] = 0.f; h1[n] = 0.f; }
  for (int k4 = 0; k4 < F / 4; ++k4) {
    int k = k4 * 4;
    float a00 = w10[(k + 0) * F + f0], a01 = w10[(k + 1) * F + f0];
    float a02 = w10[(k + 2) * F + f0], a03 = w10[(k + 3) * F + f0];
    float a10 = w10[(k + 0) * F + f1], a11 = w10[(k + 1) * F + f1];
    float a12 = w10[(k + 2) * F + f1], a13 = w10[(k + 3) * F + f1];
    float c00 = w11[(k + 0) * F + f0], c01 = w11[(k + 1) * F + f0];
    float c02 = w11[(k + 2) * F + f0], c03 = w11[(k + 3) * F + f0];
    float c10 = w11[(k + 0) * F + f1], c11 = w11[(k + 1) * F + f1];
    float c12 = w11[(k + 2) * F + f1], c13 = w11[(k + 3) * F + f1];
#pragma unroll
    for (int n = 0; n < NPB; ++n) {
      float4 xv = *(const float4*)&xs[n][k];
      float4 tv = *(const float4*)&ts[n][k];
      h0[n] += xv.x * a00 + xv.y * a01 + xv.z * a02 + xv.w * a03 +
               tv.x * c00 + tv.y * c01 + tv.z * c02 + tv.w * c03;
      h1[n] += xv.x * a10 + xv.y * a11 + xv.z * a12 + xv.w * a13 +
               tv.x * c10 + tv.y * c11 + tv.z * c12 + tv.w * c13;
    }
  }
  float bf0 = b1[f0], bf1 = b1[f1];
  float w20f0 = w20[f0], w20f1 = w20[f1];
  float w21f0 = w21[f0], w21f1 = w21[f1];
#pragma unroll
  for (int n = 0; n < NPB; ++n) {
    float hh0 = fmaxf(h0[n] + bf0, 0.f);
    float hh1 = fmaxf(h1[n] + bf1, 0.f);
    float pp = hh0 * w20f0 + hh1 * w20f1;
    float qq = hh0 * w21f0 + hh1 * w21f1;
#pragma unroll
    for (int off = 32; off > 0; off >>= 1) {
      pp += __shfl_down(pp, off);
      qq += __shfl_down(qq, off);
    }
    if (tid == 0) {
      int gn = node0 + n;
      if (gn < N) { p[gn] = pp; r[gn] = qq; }
    }
  }
}

// ---------- layer-2 aggregation + sigmoid epilogue ----------
__global__ __launch_bounds__(256) void k_gather2_final(
    const int2* __restrict__ pairs, const int* __restrict__ rp,
    const float* __restrict__ rvec, const float* __restrict__ p,
    const float* __restrict__ dinv, const float* __restrict__ b2,
    float* __restrict__ out, int N) {
  int i = blockIdx.x * 256 + threadIdx.x;
  if (i >= N) return;
  int beg = rp[i], end = rp[i + 1];
  float a = 0.f;
  for (int j = beg; j < end; ++j) {
    int2 pr = pairs[j];
    a += __int_as_float(pr.y) * rvec[pr.x];
  }
  float z = p[i] - dinv[i] * a + b2[0];
  out[i] = 1.0f / (1.0f + expf(-z));
}

// ---------- launch ----------
extern "C" void kernel_launch(void* const* d_in, const int* in_sizes, int n_in,
                              void* d_out, int out_size, void* d_ws, size_t ws_size,
                              hipStream_t stream) {
  const float* x = (const float*)d_in[0];
  const int* ei = (const int*)d_in[1];
  const float* w10 = (const float*)d_in[2];
  const float* w11 = (const float*)d_in[3];
  const float* b1 = (const float*)d_in[4];
  const float* w20 = (const float*)d_in[5];
  const float* w21 = (const float*)d_in[6];
  const float* b2 = (const float*)d_in[7];
  float* out = (float*)d_out;
  int N = in_sizes[0] / F;
  int E = in_sizes[1] / 2;
  const int* src = ei;
  const int* dst = ei + E;

  // layout (ints): dinv N | p N | r N | degA N | degB N | rp N+2 | pos N |
  //                bsum 256 | pairs 2E | acc N*F   (acc last, optional)
  size_t small_ints = 5 * (size_t)N + (N + 2) + N + 256 + 2 * (size_t)E;
  size_t need_small = small_ints * 4;
  size_t need_full = need_small + (size_t)N * F * 4;
  if (ws_size < need_small) return;

  float* dinv = (float*)d_ws;
  float* p = dinv + N;
  float* r = p + N;
  int* degA = (int*)(r + N);
  int* degB = degA + N;
  int* rp = degB + N;            // N+2 (padded so pairs stays 8B-aligned)
  int* pos = rp + N + 2;
  int* bsum = pos + N;           // 256
  int2* pairs = (int2*)(bsum + 256);
  float* acc = (float*)(bsum + 256 + 2 * (size_t)E);

  int nb = (N + SCAN_CHUNK - 1) / SCAN_CHUNK;  // <= 256 for N <= 262144

  hipMemsetAsync(degA, 0, 2 * (size_t)N * sizeof(int), stream);
  k_deg2<<<2048, 256, 0, stream>>>(src, dst, degA, degB, E);
  k_dinv<<<(N + 255) / 256, 256, 0, stream>>>(degA, dinv, N);
  k_scanA<<<nb, 256, 0, stream>>>(degB, rp, bsum, N);
  k_scanB<<<1, 256, 0, stream>>>(bsum, nb);
  k_scanC<<<(N + 255) / 256, 256, 0, stream>>>(rp, bsum, pos, N, E);
  k_fill<<<2048, 256, 0, stream>>>(src, dst, dinv, pos, pairs, E);

  int nblk = (N + NPB - 1) / NPB;
  if (ws_size >= need_full) {
    k_gather1<<<(int)(((size_t)N * 64 + 255) / 256), 256, 0, stream>>>(
        pairs, rp, x, dinv, acc, N);
    k_layer<<<nblk, 64, 0, stream>>>(x, acc, w10, w11, b1, w20, w21, p, r, N);
  } else {
    k_layer_fused<<<nblk, 64, 0, stream>>>(pairs, rp, x, dinv, w10, w11, b1, w20,
                                           w21, p, r, N);
  }
  k_gather2_final<<<(N + 255) / 256, 256, 0, stream>>>(pairs, rp, r, p, dinv, b2,
                                                       out, N);
}

// Round 5
// 528.861 us; speedup vs baseline: 5.8817x; 1.2492x over previous
//
#include <hip/hip_runtime.h>
#include <math.h>

#define F 128
#define NPB 16         // nodes per block in fallback fused layer kernel
#define SCAN_CHUNK 1024
#define CHUNK 32       // nodes per chunk in mfma layer kernel

typedef __attribute__((ext_vector_type(8))) short bf16x8;
typedef __attribute__((ext_vector_type(4))) float f32x4;

__device__ inline short f2bf(float v) {  // fp32 -> bf16 RNE
  unsigned u = __float_as_uint(v);
  unsigned r = (u + 0x7FFFu + ((u >> 16) & 1u)) >> 16;
  return (short)r;
}
__device__ inline float bf2f(short s) {
  return __uint_as_float(((unsigned)(unsigned short)s) << 16);
}

// ---------- degree count (both endpoints) ----------
__global__ __launch_bounds__(256) void k_deg2(const int* __restrict__ src,
                                              const int* __restrict__ dst,
                                              int* __restrict__ degA,
                                              int* __restrict__ degB, int E) {
  for (int i = blockIdx.x * 256 + threadIdx.x; i < E; i += gridDim.x * 256) {
    atomicAdd(&degA[src[i]], 1);
    atomicAdd(&degB[dst[i]], 1);
  }
}

__global__ __launch_bounds__(256) void k_dinv(const int* __restrict__ deg,
                                              float* __restrict__ dinv, int N) {
  int i = blockIdx.x * 256 + threadIdx.x;
  if (i < N) {
    int d = deg[i];
    dinv[i] = d > 0 ? rsqrtf((float)d) : 0.0f;
  }
}

// ---------- CSR build: 3-phase exclusive scan of in-degrees ----------
__global__ __launch_bounds__(256) void k_scanA(const int* __restrict__ deg,
                                               int* __restrict__ rp,
                                               int* __restrict__ bsum, int N) {
  __shared__ int sh[256];
  int tid = threadIdx.x;
  int base = blockIdx.x * SCAN_CHUNK + tid * 4;
  int v0 = 0, v1 = 0, v2 = 0, v3 = 0;
  if (base + 0 < N) v0 = deg[base + 0];
  if (base + 1 < N) v1 = deg[base + 1];
  if (base + 2 < N) v2 = deg[base + 2];
  if (base + 3 < N) v3 = deg[base + 3];
  int ts = v0 + v1 + v2 + v3;
  int val = ts;
  sh[tid] = val;
  __syncthreads();
  for (int off = 1; off < 256; off <<= 1) {
    int other = (tid >= off) ? sh[tid - off] : 0;
    __syncthreads();
    val += other;
    sh[tid] = val;
    __syncthreads();
  }
  int excl = val - ts;
  if (base + 0 < N) rp[base + 0] = excl;
  if (base + 1 < N) rp[base + 1] = excl + v0;
  if (base + 2 < N) rp[base + 2] = excl + v0 + v1;
  if (base + 3 < N) rp[base + 3] = excl + v0 + v1 + v2;
  if (tid == 255) bsum[blockIdx.x] = val;
}

__global__ __launch_bounds__(256) void k_scanB(int* __restrict__ bsum, int nb) {
  __shared__ int sh[256];
  int tid = threadIdx.x;
  int ts = (tid < nb) ? bsum[tid] : 0;
  int val = ts;
  sh[tid] = val;
  __syncthreads();
  for (int off = 1; off < 256; off <<= 1) {
    int other = (tid >= off) ? sh[tid - off] : 0;
    __syncthreads();
    val += other;
    sh[tid] = val;
    __syncthreads();
  }
  if (tid < nb) bsum[tid] = val - ts;  // exclusive
}

__global__ __launch_bounds__(256) void k_scanC(int* __restrict__ rp,
                                               const int* __restrict__ bsum,
                                               int* __restrict__ pos, int N, int E) {
  int i = blockIdx.x * 256 + threadIdx.x;
  if (i < N) {
    int v = rp[i] + bsum[i >> 10];
    rp[i] = v;
    pos[i] = v;
  }
  if (i == 0) rp[N] = E;
}

__global__ __launch_bounds__(256) void k_fill(const int* __restrict__ src,
                                              const int* __restrict__ dst,
                                              const float* __restrict__ dinv,
                                              int* __restrict__ pos,
                                              int2* __restrict__ pairs, int E) {
  for (int e = blockIdx.x * 256 + threadIdx.x; e < E; e += gridDim.x * 256) {
    int s = src[e];
    int d = dst[e];
    int idx = atomicAdd(&pos[d], 1);
    pairs[idx] = make_int2(s, __float_as_int(dinv[s]));
  }
}

// ---------- aggregation by gather, one wave per node ----------
// acc[i] = -dinv[i] * sum_{e: dst=i} dinv[src] * x[src]   (row of 128 floats)
__global__ __launch_bounds__(256) void k_gather1(const int2* __restrict__ pairs,
                                                 const int* __restrict__ rp,
                                                 const float* __restrict__ x,
                                                 const float* __restrict__ dinv,
                                                 float* __restrict__ acc, int N) {
  int wave = (blockIdx.x * 256 + threadIdx.x) >> 6;
  int lane = threadIdx.x & 63;
  if (wave >= N) return;
  int beg = rp[wave], end = rp[wave + 1];
  const float2* x2 = (const float2*)x;
  float ax = 0.f, ay = 0.f;
  int j = beg;
  for (; j + 1 < end; j += 2) {
    int2 p0 = pairs[j];
    int2 p1 = pairs[j + 1];
    float w0 = __int_as_float(p0.y);
    float w1 = __int_as_float(p1.y);
    float2 v0 = x2[(size_t)p0.x * 64 + lane];
    float2 v1 = x2[(size_t)p1.x * 64 + lane];
    ax += w0 * v0.x + w1 * v1.x;
    ay += w0 * v0.y + w1 * v1.y;
  }
  if (j < end) {
    int2 p0 = pairs[j];
    float w0 = __int_as_float(p0.y);
    float2 v0 = x2[(size_t)p0.x * 64 + lane];
    ax += w0 * v0.x;
    ay += w0 * v0.y;
  }
  float di = dinv[wave];
  ((float2*)acc)[(size_t)wave * 64 + lane] = make_float2(-di * ax, -di * ay);
}

// ---------- MFMA fused layer: H = relu(X@W10 + T@W11 + b1); p = H.w20; r = H.w21
// Split-bf16 (hi+lo): A*B ~= Ah*Bh + Al*Bh + Ah*Bl. Weights live in registers
// (each wave owns a 32-feature slice). Grid-stride over 32-node chunks.
__global__ __launch_bounds__(256) void k_layer_mfma(
    const float* __restrict__ x, const float* __restrict__ tsrc,
    const float* __restrict__ w10, const float* __restrict__ w11,
    const float* __restrict__ b1, const float* __restrict__ w20,
    const float* __restrict__ w21, float* __restrict__ p, float* __restrict__ r,
    int N) {
  // A-planes: [mt*4+ks][m=16][40]  (row padded 32->40 bf16: 2-way bank alias max)
  __shared__ __align__(16) short Axh[8 * 16 * 40];
  __shared__ __align__(16) short Axl[8 * 16 * 40];
  __shared__ __align__(16) short Ath[8 * 16 * 40];
  __shared__ __align__(16) short Atl[8 * 16 * 40];
  __shared__ float p_sh[CHUNK], r_sh[CHUNK];

  const int tid = threadIdx.x;
  const int wave = tid >> 6;
  const int lane = tid & 63;
  const int quad = lane >> 4;
  const int col = lane & 15;

  // ---- load B fragments (weights) into registers, once ----
  bf16x8 Bh[2][4][2], Bl[2][4][2];  // [mat][ks][nt]
  float b1f[2], w20f[2], w21f[2];
#pragma unroll
  for (int nt = 0; nt < 2; ++nt) {
    int f = wave * 32 + nt * 16 + col;
    b1f[nt] = b1[f];
    w20f[nt] = w20[f];
    w21f[nt] = w21[f];
  }
#pragma unroll
  for (int mat = 0; mat < 2; ++mat) {
    const float* w = mat ? w11 : w10;
#pragma unroll
    for (int ks = 0; ks < 4; ++ks) {
#pragma unroll
      for (int nt = 0; nt < 2; ++nt) {
        int f = wave * 32 + nt * 16 + col;
        bf16x8 h8, l8;
#pragma unroll
        for (int j = 0; j < 8; ++j) {
          float v = w[(ks * 32 + quad * 8 + j) * F + f];
          short hi = f2bf(v);
          l8[j] = f2bf(v - bf2f(hi));
          h8[j] = hi;
        }
        Bh[mat][ks][nt] = h8;
        Bl[mat][ks][nt] = l8;
      }
    }
  }

  const int nchunks = (N + CHUNK - 1) / CHUNK;
  for (int chunk = blockIdx.x; chunk < nchunks; chunk += gridDim.x) {
    int node0 = chunk * CHUNK;

    // ---- stage A (x and t rows -> hi/lo bf16, A-operand layout) ----
    {
      int nloc = tid >> 3;       // 0..31
      int k0 = (tid & 7) * 16;   // 0..112
      int gn = node0 + nloc;
      int mt = nloc >> 4, m = nloc & 15, ks = k0 >> 5, koff = k0 & 31;
      int base = ((mt * 4 + ks) * 16 + m) * 40 + koff;
      const float4* xr = (const float4*)(x + (size_t)gn * F + k0);
      const float4* tr = (const float4*)(tsrc + (size_t)gn * F + k0);
      bool ok = (gn < N);
#pragma unroll
      for (int q4 = 0; q4 < 4; ++q4) {
        float4 xv = ok ? xr[q4] : make_float4(0.f, 0.f, 0.f, 0.f);
        float4 tv = ok ? tr[q4] : make_float4(0.f, 0.f, 0.f, 0.f);
        short4 xh, xl, th, tl;
        xh.x = f2bf(xv.x); xl.x = f2bf(xv.x - bf2f(xh.x));
        xh.y = f2bf(xv.y); xl.y = f2bf(xv.y - bf2f(xh.y));
        xh.z = f2bf(xv.z); xl.z = f2bf(xv.z - bf2f(xh.z));
        xh.w = f2bf(xv.w); xl.w = f2bf(xv.w - bf2f(xh.w));
        th.x = f2bf(tv.x); tl.x = f2bf(tv.x - bf2f(th.x));
        th.y = f2bf(tv.y); tl.y = f2bf(tv.y - bf2f(th.y));
        th.z = f2bf(tv.z); tl.z = f2bf(tv.z - bf2f(th.z));
        th.w = f2bf(tv.w); tl.w = f2bf(tv.w - bf2f(th.w));
        *(short4*)&Axh[base + q4 * 4] = xh;
        *(short4*)&Axl[base + q4 * 4] = xl;
        *(short4*)&Ath[base + q4 * 4] = th;
        *(short4*)&Atl[base + q4 * 4] = tl;
      }
      if (tid < CHUNK) {  // wave 0 zeroes the reduction buffers
        p_sh[tid] = 0.f;
        r_sh[tid] = 0.f;
      }
    }
    __syncthreads();

    // ---- K loop: 96 MFMAs per wave ----
    f32x4 acc[2][2];
#pragma unroll
    for (int mt = 0; mt < 2; ++mt)
#pragma unroll
      for (int nt = 0; nt < 2; ++nt) acc[mt][nt] = (f32x4)0.f;

#pragma unroll
    for (int mt = 0; mt < 2; ++mt) {
#pragma unroll
      for (int ks = 0; ks < 4; ++ks) {
        int ab = ((mt * 4 + ks) * 16 + col) * 40 + quad * 8;
        bf16x8 axh = *(bf16x8*)&Axh[ab];
        bf16x8 axl = *(bf16x8*)&Axl[ab];
        bf16x8 ath = *(bf16x8*)&Ath[ab];
        bf16x8 atl = *(bf16x8*)&Atl[ab];
#pragma unroll
        for (int nt = 0; nt < 2; ++nt) {
          f32x4 c = acc[mt][nt];
          c = __builtin_amdgcn_mfma_f32_16x16x32_bf16(axh, Bh[0][ks][nt], c, 0, 0, 0);
          c = __builtin_amdgcn_mfma_f32_16x16x32_bf16(axl, Bh[0][ks][nt], c, 0, 0, 0);
          c = __builtin_amdgcn_mfma_f32_16x16x32_bf16(axh, Bl[0][ks][nt], c, 0, 0, 0);
          c = __builtin_amdgcn_mfma_f32_16x16x32_bf16(ath, Bh[1][ks][nt], c, 0, 0, 0);
          c = __builtin_amdgcn_mfma_f32_16x16x32_bf16(atl, Bh[1][ks][nt], c, 0, 0, 0);
          c = __builtin_amdgcn_mfma_f32_16x16x32_bf16(ath, Bl[1][ks][nt], c, 0, 0, 0);
          acc[mt][nt] = c;
        }
      }
    }

    // ---- epilogue: bias + relu + project to p,r; reduce over 16 cols ----
#pragma unroll
    for (int mt = 0; mt < 2; ++mt) {
      float pp[4], rr[4];
#pragma unroll
      for (int reg = 0; reg < 4; ++reg) {
        float h0 = fmaxf(acc[mt][0][reg] + b1f[0], 0.f);
        float h1 = fmaxf(acc[mt][1][reg] + b1f[1], 0.f);
        pp[reg] = h0 * w20f[0] + h1 * w20f[1];
        rr[reg] = h0 * w21f[0] + h1 * w21f[1];
      }
#pragma unroll
      for (int off = 1; off < 16; off <<= 1) {
#pragma unroll
        for (int reg = 0; reg < 4; ++reg) {
          pp[reg] += __shfl_xor(pp[reg], off);
          rr[reg] += __shfl_xor(rr[reg], off);
        }
      }
      if (col == 0) {
#pragma unroll
        for (int reg = 0; reg < 4; ++reg) {
          atomicAdd(&p_sh[mt * 16 + quad * 4 + reg], pp[reg]);
          atomicAdd(&r_sh[mt * 16 + quad * 4 + reg], rr[reg]);
        }
      }
    }
    __syncthreads();
    if (tid < CHUNK) {
      int gn = node0 + tid;
      if (gn < N) {
        p[gn] = p_sh[tid];
        r[gn] = r_sh[tid];
      }
    }
  }
}

// ---------- fallback: layer with neighborhood gather fused (no acc buffer) ----
__global__ __launch_bounds__(64) void k_layer_fused(
    const int2* __restrict__ pairs, const int* __restrict__ rp,
    const float* __restrict__ x, const float* __restrict__ dinv,
    const float* __restrict__ w10, const float* __restrict__ w11,
    const float* __restrict__ b1, const float* __restrict__ w20,
    const float* __restrict__ w21, float* __restrict__ p, float* __restrict__ r,
    int N) {
  __shared__ float xs[NPB][F];
  __shared__ float ts[NPB][F];
  int node0 = blockIdx.x * NPB;
  int tid = threadIdx.x;  // 0..63
  for (int idx = tid; idx < NPB * F; idx += 64) {
    int n = idx >> 7, k = idx & 127;
    int gn = node0 + n;
    xs[n][k] = (gn < N) ? x[(size_t)gn * F + k] : 0.f;
  }
  const float2* x2 = (const float2*)x;
#pragma unroll 1
  for (int n = 0; n < NPB; ++n) {
    int gn = node0 + n;
    float ax = 0.f, ay = 0.f;
    if (gn < N) {
      int beg = rp[gn], end = rp[gn + 1];
      int j = beg;
      for (; j + 1 < end; j += 2) {
        int2 p0 = pairs[j];
        int2 p1 = pairs[j + 1];
        float w0 = __int_as_float(p0.y);
        float w1 = __int_as_float(p1.y);
        float2 v0 = x2[(size_t)p0.x * 64 + tid];
        float2 v1 = x2[(size_t)p1.x * 64 + tid];
        ax += w0 * v0.x + w1 * v1.x;
        ay += w0 * v0.y + w1 * v1.y;
      }
      if (j < end) {
        int2 p0 = pairs[j];
        float w0 = __int_as_float(p0.y);
        float2 v0 = x2[(size_t)p0.x * 64 + tid];
        ax += w0 * v0.x;
        ay += w0 * v0.y;
      }
      float di = dinv[gn];
      ax *= -di;
      ay *= -di;
    }
    ((float2*)&ts[n][0])[tid] = make_float2(ax, ay);
  }
  __syncthreads();
  const int f0 = tid, f1 = tid + 64;
  float h0[NPB], h1[NPB];
#pragma unroll
  for (int n = 0; n < NPB; ++n) { h0[n] = 0.f; h1[n] = 0.f; }
  for (int k4 = 0; k4 < F / 4; ++k4) {
    int k = k4 * 4;
    float a00 = w10[(k + 0) * F + f0], a01 = w10[(k + 1) * F + f0];
    float a02 = w10[(k + 2) * F + f0], a03 = w10[(k + 3) * F + f0];
    float a10 = w10[(k + 0) * F + f1], a11 = w10[(k + 1) * F + f1];
    float a12 = w10[(k + 2) * F + f1], a13 = w10[(k + 3) * F + f1];
    float c00 = w11[(k + 0) * F + f0], c01 = w11[(k + 1) * F + f0];
    float c02 = w11[(k + 2) * F + f0], c03 = w11[(k + 3) * F + f0];
    float c10 = w11[(k + 0) * F + f1], c11 = w11[(k + 1) * F + f1];
    float c12 = w11[(k + 2) * F + f1], c13 = w11[(k + 3) * F + f1];
#pragma unroll
    for (int n = 0; n < NPB; ++n) {
      float4 xv = *(const float4*)&xs[n][k];
      float4 tv = *(const float4*)&ts[n][k];
      h0[n] += xv.x * a00 + xv.y * a01 + xv.z * a02 + xv.w * a03 +
               tv.x * c00 + tv.y * c01 + tv.z * c02 + tv.w * c03;
      h1[n] += xv.x * a10 + xv.y * a11 + xv.z * a12 + xv.w * a13 +
               tv.x * c10 + tv.y * c11 + tv.z * c12 + tv.w * c13;
    }
  }
  float bf0 = b1[f0], bf1 = b1[f1];
  float w20f0 = w20[f0], w20f1 = w20[f1];
  float w21f0 = w21[f0], w21f1 = w21[f1];
#pragma unroll
  for (int n = 0; n < NPB; ++n) {
    float hh0 = fmaxf(h0[n] + bf0, 0.f);
    float hh1 = fmaxf(h1[n] + bf1, 0.f);
    float pp = hh0 * w20f0 + hh1 * w20f1;
    float qq = hh0 * w21f0 + hh1 * w21f1;
#pragma unroll
    for (int off = 32; off > 0; off >>= 1) {
      pp += __shfl_down(pp, off);
      qq += __shfl_down(qq, off);
    }
    if (tid == 0) {
      int gn = node0 + n;
      if (gn < N) { p[gn] = pp; r[gn] = qq; }
    }
  }
}

// ---------- layer-2 aggregation + sigmoid epilogue ----------
__global__ __launch_bounds__(256) void k_gather2_final(
    const int2* __restrict__ pairs, const int* __restrict__ rp,
    const float* __restrict__ rvec, const float* __restrict__ p,
    const float* __restrict__ dinv, const float* __restrict__ b2,
    float* __restrict__ out, int N) {
  int i = blockIdx.x * 256 + threadIdx.x;
  if (i >= N) return;
  int beg = rp[i], end = rp[i + 1];
  float a = 0.f;
  for (int j = beg; j < end; ++j) {
    int2 pr = pairs[j];
    a += __int_as_float(pr.y) * rvec[pr.x];
  }
  float z = p[i] - dinv[i] * a + b2[0];
  out[i] = 1.0f / (1.0f + expf(-z));
}

// ---------- launch ----------
extern "C" void kernel_launch(void* const* d_in, const int* in_sizes, int n_in,
                              void* d_out, int out_size, void* d_ws, size_t ws_size,
                              hipStream_t stream) {
  const float* x = (const float*)d_in[0];
  const int* ei = (const int*)d_in[1];
  const float* w10 = (const float*)d_in[2];
  const float* w11 = (const float*)d_in[3];
  const float* b1 = (const float*)d_in[4];
  const float* w20 = (const float*)d_in[5];
  const float* w21 = (const float*)d_in[6];
  const float* b2 = (const float*)d_in[7];
  float* out = (float*)d_out;
  int N = in_sizes[0] / F;
  int E = in_sizes[1] / 2;
  const int* src = ei;
  const int* dst = ei + E;

  // layout (ints): dinv N | p N | r N | degA N | degB N | rp N+2 | pos N |
  //                bsum 256 | pairs 2E | acc N*F   (acc last, optional)
  size_t small_ints = 5 * (size_t)N + (N + 2) + N + 256 + 2 * (size_t)E;
  size_t need_small = small_ints * 4;
  size_t need_full = need_small + (size_t)N * F * 4;
  if (ws_size < need_small) return;

  float* dinv = (float*)d_ws;
  float* p = dinv + N;
  float* r = p + N;
  int* degA = (int*)(r + N);
  int* degB = degA + N;
  int* rp = degB + N;  // N+2 (padded so pairs stays 8B-aligned)
  int* pos = rp + N + 2;
  int* bsum = pos + N;  // 256
  int2* pairs = (int2*)(bsum + 256);
  float* acc = (float*)(bsum + 256 + 2 * (size_t)E);

  int nb = (N + SCAN_CHUNK - 1) / SCAN_CHUNK;  // <= 256 for N <= 262144

  hipMemsetAsync(degA, 0, 2 * (size_t)N * sizeof(int), stream);
  k_deg2<<<2048, 256, 0, stream>>>(src, dst, degA, degB, E);
  k_dinv<<<(N + 255) / 256, 256, 0, stream>>>(degA, dinv, N);
  k_scanA<<<nb, 256, 0, stream>>>(degB, rp, bsum, N);
  k_scanB<<<1, 256, 0, stream>>>(bsum, nb);
  k_scanC<<<(N + 255) / 256, 256, 0, stream>>>(rp, bsum, pos, N, E);
  k_fill<<<2048, 256, 0, stream>>>(src, dst, dinv, pos, pairs, E);

  if (ws_size >= need_full) {
    k_gather1<<<(int)(((size_t)N * 64 + 255) / 256), 256, 0, stream>>>(
        pairs, rp, x, dinv, acc, N);
    k_layer_mfma<<<512, 256, 0, stream>>>(x, acc, w10, w11, b1, w20, w21, p, r, N);
  } else {
    int nblk = (N + NPB - 1) / NPB;
    k_layer_fused<<<nblk, 64, 0, stream>>>(pairs, rp, x, dinv, w10, w11, b1, w20,
                                           w21, p, r, N);
  }
  k_gather2_final<<<(N + 255) / 256, 256, 0, stream>>>(pairs, rp, r, p, dinv, b2,
                                                       out, N);
}

// Round 6
// 516.148 us; speedup vs baseline: 6.0266x; 1.0246x over previous
//
#include <hip/hip_runtime.h>
#include <math.h>

#define F 128
#define SCAN_CHUNK 1024
#define CHUNK 32  // nodes per chunk in mfma layer kernel

typedef __attribute__((ext_vector_type(8))) short bf16x8;
typedef __attribute__((ext_vector_type(4))) float f32x4;

__device__ inline unsigned short f2bf(float v) {  // fp32 -> bf16 RNE
  unsigned u = __float_as_uint(v);
  unsigned r = (u + 0x7FFFu + ((u >> 16) & 1u)) >> 16;
  return (unsigned short)r;
}
__device__ inline float bf2f(unsigned short s) {
  return __uint_as_float(((unsigned)s) << 16);
}

// ---------- prep: degree count (both endpoints) + x -> bf16 copy ----------
__global__ __launch_bounds__(256) void k_prep(const int* __restrict__ src,
                                              const int* __restrict__ dst,
                                              const float* __restrict__ x,
                                              int* __restrict__ degA,
                                              int* __restrict__ degB,
                                              unsigned short* __restrict__ xb,
                                              int E, int NF4) {
  int t0 = blockIdx.x * 256 + threadIdx.x;
  int stride = gridDim.x * 256;
  for (int i = t0; i < E; i += stride) {
    atomicAdd(&degA[src[i]], 1);
    atomicAdd(&degB[dst[i]], 1);
  }
  const float4* x4 = (const float4*)x;
  ushort4* xb4 = (ushort4*)xb;
  for (int i = t0; i < NF4; i += stride) {
    float4 v = x4[i];
    ushort4 o;
    o.x = f2bf(v.x);
    o.y = f2bf(v.y);
    o.z = f2bf(v.z);
    o.w = f2bf(v.w);
    xb4[i] = o;
  }
}

// ---------- CSR build: 3-phase exclusive scan of in-degrees ----------
__global__ __launch_bounds__(256) void k_scanA(const int* __restrict__ deg,
                                               int* __restrict__ rp,
                                               int* __restrict__ bsum, int N) {
  __shared__ int sh[256];
  int tid = threadIdx.x;
  int base = blockIdx.x * SCAN_CHUNK + tid * 4;
  int v0 = 0, v1 = 0, v2 = 0, v3 = 0;
  if (base + 0 < N) v0 = deg[base + 0];
  if (base + 1 < N) v1 = deg[base + 1];
  if (base + 2 < N) v2 = deg[base + 2];
  if (base + 3 < N) v3 = deg[base + 3];
  int ts = v0 + v1 + v2 + v3;
  int val = ts;
  sh[tid] = val;
  __syncthreads();
  for (int off = 1; off < 256; off <<= 1) {
    int other = (tid >= off) ? sh[tid - off] : 0;
    __syncthreads();
    val += other;
    sh[tid] = val;
    __syncthreads();
  }
  int excl = val - ts;
  if (base + 0 < N) rp[base + 0] = excl;
  if (base + 1 < N) rp[base + 1] = excl + v0;
  if (base + 2 < N) rp[base + 2] = excl + v0 + v1;
  if (base + 3 < N) rp[base + 3] = excl + v0 + v1 + v2;
  if (tid == 255) bsum[blockIdx.x] = val;
}

__global__ __launch_bounds__(256) void k_scanB(int* __restrict__ bsum, int nb) {
  __shared__ int sh[256];
  int tid = threadIdx.x;
  int ts = (tid < nb) ? bsum[tid] : 0;
  int val = ts;
  sh[tid] = val;
  __syncthreads();
  for (int off = 1; off < 256; off <<= 1) {
    int other = (tid >= off) ? sh[tid - off] : 0;
    __syncthreads();
    val += other;
    sh[tid] = val;
    __syncthreads();
  }
  if (tid < nb) bsum[tid] = val - ts;  // exclusive
}

// scanC + dinv fused
__global__ __launch_bounds__(256) void k_scanC(int* __restrict__ rp,
                                               const int* __restrict__ bsum,
                                               int* __restrict__ pos,
                                               const int* __restrict__ degA,
                                               float* __restrict__ dinv, int N,
                                               int E) {
  int i = blockIdx.x * 256 + threadIdx.x;
  if (i < N) {
    int v = rp[i] + bsum[i >> 10];
    rp[i] = v;
    pos[i] = v;
    int d = degA[i];
    dinv[i] = d > 0 ? rsqrtf((float)d) : 0.0f;
  }
  if (i == 0) rp[N] = E;
}

__global__ __launch_bounds__(256) void k_fill(const int* __restrict__ src,
                                              const int* __restrict__ dst,
                                              int* __restrict__ pos,
                                              int* __restrict__ pairs, int E) {
  for (int e = blockIdx.x * 256 + threadIdx.x; e < E; e += gridDim.x * 256) {
    int s = src[e];
    int d = dst[e];
    int idx = atomicAdd(&pos[d], 1);
    pairs[idx] = s;
  }
}

// ---------- aggregation by gather from bf16 x, one wave per node ----------
// tb[i] = bf16( -dinv[i] * sum_{e: dst=i} dinv[src] * x[src] )
// Two edges processed per wave iteration (half-wave each, 8 B/lane).
__global__ __launch_bounds__(256) void k_gather1b(
    const int* __restrict__ pairs, const int* __restrict__ rp,
    const unsigned short* __restrict__ xb, const float* __restrict__ dinv,
    unsigned short* __restrict__ tb, int N) {
  int node = (blockIdx.x * 256 + threadIdx.x) >> 6;
  if (node >= N) return;
  int lane = threadIdx.x & 63;
  int half = lane >> 5;
  int li = lane & 31;
  int beg = rp[node], end = rp[node + 1];
  const uint2* x2 = (const uint2*)xb;
  float a0 = 0.f, a1 = 0.f, a2 = 0.f, a3 = 0.f;
  int j = beg + half;
  for (; j + 2 < end; j += 4) {
    int s0 = pairs[j];
    int s1 = pairs[j + 2];
    float w0 = dinv[s0];
    float w1 = dinv[s1];
    uint2 v0 = x2[(size_t)s0 * 32 + li];
    uint2 v1 = x2[(size_t)s1 * 32 + li];
    a0 += w0 * bf2f((unsigned short)v0.x) + w1 * bf2f((unsigned short)v1.x);
    a1 += w0 * bf2f((unsigned short)(v0.x >> 16)) +
          w1 * bf2f((unsigned short)(v1.x >> 16));
    a2 += w0 * bf2f((unsigned short)v0.y) + w1 * bf2f((unsigned short)v1.y);
    a3 += w0 * bf2f((unsigned short)(v0.y >> 16)) +
          w1 * bf2f((unsigned short)(v1.y >> 16));
  }
  for (; j < end; j += 2) {
    int s0 = pairs[j];
    float w0 = dinv[s0];
    uint2 v0 = x2[(size_t)s0 * 32 + li];
    a0 += w0 * bf2f((unsigned short)v0.x);
    a1 += w0 * bf2f((unsigned short)(v0.x >> 16));
    a2 += w0 * bf2f((unsigned short)v0.y);
    a3 += w0 * bf2f((unsigned short)(v0.y >> 16));
  }
  a0 += __shfl_xor(a0, 32);
  a1 += __shfl_xor(a1, 32);
  a2 += __shfl_xor(a2, 32);
  a3 += __shfl_xor(a3, 32);
  if (half == 0) {
    float nd = -dinv[node];
    uint2 o;
    o.x = ((unsigned)f2bf(nd * a1) << 16) | f2bf(nd * a0);
    o.y = ((unsigned)f2bf(nd * a3) << 16) | f2bf(nd * a2);
    ((uint2*)tb)[(size_t)node * 32 + li] = o;
  }
}

// ---------- MFMA fused layer: H = relu(X@W10 + T@W11 + b1); p=H.w20; r2=dinv*(H.w21)
// X split hi/lo bf16 (3 terms); T already bf16 (2 terms). Weights in registers.
__global__ __launch_bounds__(256) void k_layer_mfma(
    const float* __restrict__ x, const unsigned short* __restrict__ tb,
    const float* __restrict__ dinv, const float* __restrict__ w10,
    const float* __restrict__ w11, const float* __restrict__ b1,
    const float* __restrict__ w20, const float* __restrict__ w21,
    float* __restrict__ p, float* __restrict__ r, int N) {
  // A-planes: [mt*4+ks][m=16][40]  (row padded 32->40 bf16)
  __shared__ __align__(16) short Axh[8 * 16 * 40];
  __shared__ __align__(16) short Axl[8 * 16 * 40];
  __shared__ __align__(16) short At[8 * 16 * 40];
  __shared__ float p_sh[CHUNK], r_sh[CHUNK];

  const int tid = threadIdx.x;
  const int wave = tid >> 6;
  const int lane = tid & 63;
  const int quad = lane >> 4;
  const int col = lane & 15;

  // ---- load B fragments (weights) into registers, once ----
  bf16x8 Bh[2][4][2], Bl[2][4][2];  // [mat][ks][nt]
  float b1f[2], w20f[2], w21f[2];
#pragma unroll
  for (int nt = 0; nt < 2; ++nt) {
    int f = wave * 32 + nt * 16 + col;
    b1f[nt] = b1[f];
    w20f[nt] = w20[f];
    w21f[nt] = w21[f];
  }
#pragma unroll
  for (int mat = 0; mat < 2; ++mat) {
    const float* w = mat ? w11 : w10;
#pragma unroll
    for (int ks = 0; ks < 4; ++ks) {
#pragma unroll
      for (int nt = 0; nt < 2; ++nt) {
        int f = wave * 32 + nt * 16 + col;
        bf16x8 h8, l8;
#pragma unroll
        for (int j = 0; j < 8; ++j) {
          float v = w[(ks * 32 + quad * 8 + j) * F + f];
          unsigned short hi = f2bf(v);
          l8[j] = (short)f2bf(v - bf2f(hi));
          h8[j] = (short)hi;
        }
        Bh[mat][ks][nt] = h8;
        Bl[mat][ks][nt] = l8;
      }
    }
  }

  const int nchunks = (N + CHUNK - 1) / CHUNK;
  for (int chunk = blockIdx.x; chunk < nchunks; chunk += gridDim.x) {
    int node0 = chunk * CHUNK;
    __syncthreads();  // protect LDS reuse across chunk iterations

    // ---- stage A: x rows -> hi/lo bf16; t rows copied (already bf16) ----
    {
      int nloc = tid >> 3;      // 0..31
      int k0 = (tid & 7) * 16;  // 0..112
      int gn = node0 + nloc;
      int mt = nloc >> 4, m = nloc & 15, ks = k0 >> 5, koff = k0 & 31;
      int base = ((mt * 4 + ks) * 16 + m) * 40 + koff;
      const float4* xr = (const float4*)(x + (size_t)gn * F + k0);
      const uint2* tr = (const uint2*)(tb + (size_t)gn * F + k0);
      bool ok = (gn < N);
#pragma unroll
      for (int q4 = 0; q4 < 4; ++q4) {
        float4 xv = ok ? xr[q4] : make_float4(0.f, 0.f, 0.f, 0.f);
        uint2 tv = ok ? tr[q4] : make_uint2(0u, 0u);
        short4 xh, xl;
        unsigned short h;
        h = f2bf(xv.x); xl.x = (short)f2bf(xv.x - bf2f(h)); xh.x = (short)h;
        h = f2bf(xv.y); xl.y = (short)f2bf(xv.y - bf2f(h)); xh.y = (short)h;
        h = f2bf(xv.z); xl.z = (short)f2bf(xv.z - bf2f(h)); xh.z = (short)h;
        h = f2bf(xv.w); xl.w = (short)f2bf(xv.w - bf2f(h)); xh.w = (short)h;
        *(short4*)&Axh[base + q4 * 4] = xh;
        *(short4*)&Axl[base + q4 * 4] = xl;
        *(uint2*)&At[base + q4 * 4] = tv;
      }
      if (tid < CHUNK) {  // zero the reduction buffers
        p_sh[tid] = 0.f;
        r_sh[tid] = 0.f;
      }
    }
    __syncthreads();

    // ---- K loop: 80 MFMAs per wave ----
    f32x4 acc[2][2];
#pragma unroll
    for (int mt = 0; mt < 2; ++mt)
#pragma unroll
      for (int nt = 0; nt < 2; ++nt) acc[mt][nt] = (f32x4)0.f;

#pragma unroll
    for (int mt = 0; mt < 2; ++mt) {
#pragma unroll
      for (int ks = 0; ks < 4; ++ks) {
        int ab = ((mt * 4 + ks) * 16 + col) * 40 + quad * 8;
        bf16x8 axh = *(bf16x8*)&Axh[ab];
        bf16x8 axl = *(bf16x8*)&Axl[ab];
        bf16x8 at = *(bf16x8*)&At[ab];
#pragma unroll
        for (int nt = 0; nt < 2; ++nt) {
          f32x4 c = acc[mt][nt];
          c = __builtin_amdgcn_mfma_f32_16x16x32_bf16(axh, Bh[0][ks][nt], c, 0, 0, 0);
          c = __builtin_amdgcn_mfma_f32_16x16x32_bf16(axl, Bh[0][ks][nt], c, 0, 0, 0);
          c = __builtin_amdgcn_mfma_f32_16x16x32_bf16(axh, Bl[0][ks][nt], c, 0, 0, 0);
          c = __builtin_amdgcn_mfma_f32_16x16x32_bf16(at, Bh[1][ks][nt], c, 0, 0, 0);
          c = __builtin_amdgcn_mfma_f32_16x16x32_bf16(at, Bl[1][ks][nt], c, 0, 0, 0);
          acc[mt][nt] = c;
        }
      }
    }

    // ---- epilogue: bias + relu + project to p,r; reduce over 16 cols ----
#pragma unroll
    for (int mt = 0; mt < 2; ++mt) {
      float pp[4], rr[4];
#pragma unroll
      for (int reg = 0; reg < 4; ++reg) {
        float h0 = fmaxf(acc[mt][0][reg] + b1f[0], 0.f);
        float h1 = fmaxf(acc[mt][1][reg] + b1f[1], 0.f);
        pp[reg] = h0 * w20f[0] + h1 * w20f[1];
        rr[reg] = h0 * w21f[0] + h1 * w21f[1];
      }
#pragma unroll
      for (int off = 1; off < 16; off <<= 1) {
#pragma unroll
        for (int reg = 0; reg < 4; ++reg) {
          pp[reg] += __shfl_xor(pp[reg], off);
          rr[reg] += __shfl_xor(rr[reg], off);
        }
      }
      if (col == 0) {
#pragma unroll
        for (int reg = 0; reg < 4; ++reg) {
          atomicAdd(&p_sh[mt * 16 + quad * 4 + reg], pp[reg]);
          atomicAdd(&r_sh[mt * 16 + quad * 4 + reg], rr[reg]);
        }
      }
    }
    __syncthreads();
    if (tid < CHUNK) {
      int gn = node0 + tid;
      if (gn < N) {
        p[gn] = p_sh[tid];
        r[gn] = dinv[gn] * r_sh[tid];  // fold dinv_src for layer-2 gather
      }
    }
  }
}

// ---------- layer-2 aggregation + sigmoid epilogue ----------
__global__ __launch_bounds__(256) void k_gather2_final(
    const int* __restrict__ pairs, const int* __restrict__ rp,
    const float* __restrict__ r2, const float* __restrict__ p,
    const float* __restrict__ dinv, const float* __restrict__ b2,
    float* __restrict__ out, int N) {
  int i = blockIdx.x * 256 + threadIdx.x;
  if (i >= N) return;
  int beg = rp[i], end = rp[i + 1];
  float a = 0.f;
  for (int j = beg; j < end; ++j) a += r2[pairs[j]];
  float z = p[i] - dinv[i] * a + b2[0];
  out[i] = 1.0f / (1.0f + expf(-z));
}

// ---------- launch ----------
extern "C" void kernel_launch(void* const* d_in, const int* in_sizes, int n_in,
                              void* d_out, int out_size, void* d_ws, size_t ws_size,
                              hipStream_t stream) {
  const float* x = (const float*)d_in[0];
  const int* ei = (const int*)d_in[1];
  const float* w10 = (const float*)d_in[2];
  const float* w11 = (const float*)d_in[3];
  const float* b1 = (const float*)d_in[4];
  const float* w20 = (const float*)d_in[5];
  const float* w21 = (const float*)d_in[6];
  const float* b2 = (const float*)d_in[7];
  float* out = (float*)d_out;
  int N = in_sizes[0] / F;
  int E = in_sizes[1] / 2;
  const int* src = ei;
  const int* dst = ei + E;

  // workspace layout (all 16B-aligned): ~60.5 MB total
  size_t off = 0;
  char* base = (char*)d_ws;
  auto take = [&](size_t bytes) {
    void* ptr = base + off;
    off += (bytes + 15) & ~(size_t)15;
    return ptr;
  };
  float* dinv = (float*)take((size_t)N * 4);
  float* p = (float*)take((size_t)N * 4);
  float* r = (float*)take((size_t)N * 4);
  int* degA = (int*)take((size_t)N * 4);
  int* degB = (int*)take((size_t)N * 4);
  int* rp = (int*)take(((size_t)N + 1) * 4);
  int* pos = (int*)take((size_t)N * 4);
  int* bsum = (int*)take(256 * 4);
  int* pairs = (int*)take((size_t)E * 4);
  unsigned short* xb = (unsigned short*)take((size_t)N * F * 2);
  unsigned short* tb = (unsigned short*)take((size_t)N * F * 2);
  if (off > ws_size) return;

  int nb = (N + SCAN_CHUNK - 1) / SCAN_CHUNK;  // <= 256 for N <= 262144
  int NF4 = N * (F / 4);

  hipMemsetAsync(degA, 0, 2 * (size_t)N * sizeof(int), stream);  // degA+degB
  k_prep<<<2048, 256, 0, stream>>>(src, dst, x, degA, degB, xb, E, NF4);
  k_scanA<<<nb, 256, 0, stream>>>(degB, rp, bsum, N);
  k_scanB<<<1, 256, 0, stream>>>(bsum, nb);
  k_scanC<<<(N + 255) / 256, 256, 0, stream>>>(rp, bsum, pos, degA, dinv, N, E);
  k_fill<<<2048, 256, 0, stream>>>(src, dst, pos, pairs, E);
  k_gather1b<<<(N + 3) / 4, 256, 0, stream>>>(pairs, rp, xb, dinv, tb, N);
  k_layer_mfma<<<512, 256, 0, stream>>>(x, tb, dinv, w10, w11, b1, w20, w21, p, r,
                                        N);
  k_gather2_final<<<(N + 255) / 256, 256, 0, stream>>>(pairs, rp, r, p, dinv, b2,
                                                       out, N);
}